// Round 6
// baseline (553.695 us; speedup 1.0000x reference)
//
#include <hip/hip_runtime.h>
#include <math.h>

#define SB 4
#define SS 2048
#define SD 1024
#define SH 16
#define KTOP 409   // max(2048//5, 1)
#define KSL 8      // xbar split-K slices
#define KPS 52     // ceil(KTOP/KSL)

typedef float f32x4  __attribute__((ext_vector_type(4)));
typedef short bf16x8 __attribute__((ext_vector_type(8)));
typedef short s16x4  __attribute__((ext_vector_type(4)));

__device__ __forceinline__ short f2bf(float x) {
  unsigned u = __float_as_uint(x);
  u += 0x7fff + ((u >> 16) & 1);           // RNE
  return (short)(u >> 16);
}
__device__ __forceinline__ float bf2f(short s) {
  return __uint_as_float(((unsigned)(unsigned short)s) << 16);
}

// ---------------- P-1: forward twiddle table w_j = exp(-2pi i j/2048) ----------
__global__ __launch_bounds__(256) void twiddle_k(float2* __restrict__ twtab) {
  int j = blockIdx.x * 256 + threadIdx.x;   // < 1024
  float a = 6.2831853071795864769f * (float)j / 2048.0f;
  twtab[j] = make_float2(cosf(a), -sinf(a));
}

// ---------------- P0: transpose + split W[k][n] -> Wt[n][{hi:0..1023|lo:1024..2047}]
__global__ __launch_bounds__(256) void splitwt_k(
    const float* __restrict__ wq, const float* __restrict__ wk,
    short* __restrict__ wqt, short* __restrict__ wkt)
{
  const float* W = blockIdx.z ? wk : wq;
  short* Wt = blockIdx.z ? wkt : wqt;
  const int n0 = blockIdx.x * 64, k0 = blockIdx.y * 64;
  __shared__ float T[64][65];
  const int tid = threadIdx.x;
#pragma unroll
  for (int l = 0; l < 4; ++l) {
    int idx = tid + l * 256;
    int r = idx >> 4, c4 = (idx & 15) << 2;
    float4 v = *(const float4*)&W[(size_t)(k0 + r) * SD + n0 + c4];
    T[r][c4 + 0] = v.x; T[r][c4 + 1] = v.y; T[r][c4 + 2] = v.z; T[r][c4 + 3] = v.w;
  }
  __syncthreads();
#pragma unroll
  for (int l = 0; l < 4; ++l) {
    int idx = tid + l * 256;
    int nr = idx >> 4, k4 = (idx & 15) << 2;
    s16x4 hi, lo;
#pragma unroll
    for (int j = 0; j < 4; ++j) {
      float x = T[k4 + j][nr];
      short hb = f2bf(x);
      hi[j] = hb; lo[j] = f2bf(x - bf2f(hb));
    }
    *(s16x4*)&Wt[(size_t)(n0 + nr) * 2048 + k0 + k4] = hi;
    *(s16x4*)&Wt[(size_t)(n0 + nr) * 2048 + 1024 + k0 + k4] = lo;
  }
}

// ---------------- K1: split-bf16 MFMA projection (16x16x32), 64x64 tile --------
// grid (16 n, 32 m, 2 {q,k}), block 256 = 4 waves in 2x2, 32x32 per wave.
__global__ __launch_bounds__(256) void proj_k(
    const float* __restrict__ xq, const short* __restrict__ Wq,
    const float* __restrict__ bq, float* __restrict__ Qt,
    const float* __restrict__ xk, const short* __restrict__ Wk,
    const float* __restrict__ bk, float* __restrict__ Kt)
{
  const float* X; const short* Wt; const float* bias; float* Out;
  if (blockIdx.z == 0) { X = xq; Wt = Wq; bias = bq; Out = Qt; }
  else                 { X = xk; Wt = Wk; bias = bk; Out = Kt; }
  const int n0 = blockIdx.x * 64, m0 = blockIdx.y * 64;
  __shared__ __align__(16) short Ah[64 * 64];
  __shared__ __align__(16) short Al[64 * 64];
  __shared__ __align__(16) short Bh[64 * 64];
  __shared__ __align__(16) short Bl[64 * 64];
  const int tid = threadIdx.x;
  const int wave = tid >> 6, lane = tid & 63, l15 = lane & 15, kq = lane >> 4;
  const int wr = wave >> 1, wc = wave & 1;
  f32x4 acc[2][2];
#pragma unroll
  for (int i = 0; i < 2; ++i)
#pragma unroll
    for (int j = 0; j < 2; ++j)
#pragma unroll
      for (int r = 0; r < 4; ++r) acc[i][j][r] = 0.f;
  float bval[2];
#pragma unroll
  for (int j = 0; j < 2; ++j) bval[j] = bias[n0 + wc * 32 + j * 16 + l15];

  for (int s = 0; s < 16; ++s) {
    __syncthreads();
#pragma unroll
    for (int l = 0; l < 2; ++l) {
      int idx = tid + l * 256;
      int row = idx >> 3, seg = idx & 7;
      const float* src = &X[(size_t)(m0 + row) * SD + s * 64 + seg * 8];
      float4 va = *(const float4*)src;
      float4 vb = *(const float4*)(src + 4);
      float xs[8] = {va.x, va.y, va.z, va.w, vb.x, vb.y, vb.z, vb.w};
      bf16x8 hi, lo;
#pragma unroll
      for (int j = 0; j < 8; ++j) {
        short hb = f2bf(xs[j]);
        hi[j] = hb; lo[j] = f2bf(xs[j] - bf2f(hb));
      }
      int dst = row * 64 + ((seg ^ (row & 7)) << 3);
      *(bf16x8*)&Ah[dst] = hi;
      *(bf16x8*)&Al[dst] = lo;
    }
#pragma unroll
    for (int l = 0; l < 2; ++l) {
      int idx = tid + l * 256;
      int row = idx >> 3, seg = idx & 7;
      int d = row * 64 + ((seg ^ (row & 7)) << 3);
      *(bf16x8*)&Bh[d] = *(const bf16x8*)&Wt[(size_t)(n0 + row) * 2048 + s * 64 + seg * 8];
      *(bf16x8*)&Bl[d] = *(const bf16x8*)&Wt[(size_t)(n0 + row) * 2048 + 1024 + s * 64 + seg * 8];
    }
    __syncthreads();
#pragma unroll
    for (int ks = 0; ks < 2; ++ks) {
      int seg = ks * 4 + kq;
      bf16x8 ah[2], al[2], bh[2], bl[2];
#pragma unroll
      for (int i = 0; i < 2; ++i) {
        int ar = wr * 32 + i * 16 + l15;
        int addr = ar * 64 + ((seg ^ (ar & 7)) << 3);
        ah[i] = *(const bf16x8*)&Ah[addr];
        al[i] = *(const bf16x8*)&Al[addr];
      }
#pragma unroll
      for (int j = 0; j < 2; ++j) {
        int br = wc * 32 + j * 16 + l15;
        int addr = br * 64 + ((seg ^ (br & 7)) << 3);
        bh[j] = *(const bf16x8*)&Bh[addr];
        bl[j] = *(const bf16x8*)&Bl[addr];
      }
#pragma unroll
      for (int i = 0; i < 2; ++i)
#pragma unroll
        for (int j = 0; j < 2; ++j) {
          acc[i][j] = __builtin_amdgcn_mfma_f32_16x16x32_bf16(ah[i], bh[j], acc[i][j], 0, 0, 0);
          acc[i][j] = __builtin_amdgcn_mfma_f32_16x16x32_bf16(al[i], bh[j], acc[i][j], 0, 0, 0);
          acc[i][j] = __builtin_amdgcn_mfma_f32_16x16x32_bf16(ah[i], bl[j], acc[i][j], 0, 0, 0);
        }
    }
  }
#pragma unroll
  for (int i = 0; i < 2; ++i)
#pragma unroll
    for (int j = 0; j < 2; ++j) {
      int n = n0 + wc * 32 + j * 16 + l15;
      int tb = m0 + wr * 32 + i * 16 + kq * 4;
      float4 v = make_float4(acc[i][j][0] + bval[j], acc[i][j][1] + bval[j],
                             acc[i][j][2] + bval[j], acc[i][j][3] + bval[j]);
      *(float4*)&Out[(size_t)n * SS + tb] = v;
    }
}

// ---------------- K2: packed FFT (re=q, im=k) + cross-spectrum accumulate ------
// grid (64 d-cols, 16 heads) per batch; 1 column per block.
__global__ __launch_bounds__(256) void fftcorr_k(
    const float* __restrict__ Qt, const float* __restrict__ Kt,
    float* __restrict__ Pb, const float2* __restrict__ twtab)
{
  const int dg = blockIdx.x, h = blockIdx.y;
  __shared__ float re[2048], im[2048];
  __shared__ float twc[1024], tws[1024];
  const int tid = threadIdx.x;
  for (int j = tid; j < 1024; j += 256) {
    float2 t = twtab[j];
    twc[j] = t.x; tws[j] = t.y;
  }
  const int n = h * 64 + dg;
#pragma unroll
  for (int l = 0; l < 8; ++l) {
    int t = tid + l * 256;
    int rv = __brev((unsigned)t) >> 21;
    re[rv] = Qt[(size_t)n * SS + t];
    im[rv] = Kt[(size_t)n * SS + t];
  }
  __syncthreads();
  for (int s = 1; s <= 11; ++s) {
    const int half = 1 << (s - 1);
    const int m = half << 1;
    const int tshift = 11 - s;
#pragma unroll
    for (int l = 0; l < 4; ++l) {
      int bfly = tid + l * 256;
      int g = bfly >> (s - 1), p = bfly & (half - 1);
      int i0 = g * m + p, i1 = i0 + half;
      int tj = p << tshift;
      float wr_ = twc[tj], wi_ = tws[tj];
      float xr = re[i1], xi = im[i1];
      float tr = wr_ * xr - wi_ * xi;
      float ti = wr_ * xi + wi_ * xr;
      float ur = re[i0], ui = im[i0];
      re[i1] = ur - tr; im[i1] = ui - ti;
      re[i0] = ur + tr; im[i0] = ui + ti;
    }
    __syncthreads();
  }
#pragma unroll
  for (int l = 0; l < 8; ++l) {
    int f = tid + l * 256;
    int fc = (2048 - f) & 2047;
    float Zr = re[f], Zi = im[f];
    float Zcr = re[fc], Zci = -im[fc];
    float Qr = 0.5f * (Zr + Zcr), Qi = 0.5f * (Zi + Zci);
    float Kr = 0.5f * (Zi - Zci), Ki = -0.5f * (Zr - Zcr);
    atomicAdd(&Pb[((size_t)h * SS + f) * 2 + 0], Qr * Kr + Qi * Ki);
    atomicAdd(&Pb[((size_t)h * SS + f) * 2 + 1], Qi * Kr - Qr * Ki);
  }
}

// ---------------- K3: inverse FFT + byte-radix top-409 + softmax, per (b,h) ----
__global__ __launch_bounds__(256) void ifft_topk_k(
    const float* __restrict__ P, const float2* __restrict__ twtab,
    int* __restrict__ sidx, float* __restrict__ sw)
{
  const int bh = blockIdx.x;
  __shared__ float re[2048], im[2048];
  __shared__ float twc[1024], tws[1024];
  __shared__ unsigned keys[2048];
  __shared__ int el_i[KTOP];
  __shared__ float el_w[KTOP];
  __shared__ int hist[256];
  __shared__ int scan_sh[256];
  __shared__ int cnt2, tiecnt, sel_v;
  __shared__ unsigned kmax_sh;
  __shared__ float Zsh;
  const int tid = threadIdx.x;
  const float SCL = 1.0f / (2048.0f * 512.0f);   // 1/N * 1/(dh*sqrt(dh))

  for (int j = tid; j < 1024; j += 256) {
    float2 t = twtab[j];
    twc[j] = t.x; tws[j] = -t.y;   // inverse = conj of forward
  }
  if (tid == 0) { cnt2 = 0; tiecnt = 0; kmax_sh = 0u; Zsh = 0.f; }
#pragma unroll
  for (int l = 0; l < 8; ++l) {
    int f = tid + l * 256;
    int rv = __brev((unsigned)f) >> 21;
    re[rv] = P[((size_t)bh * SS + f) * 2 + 0];
    im[rv] = P[((size_t)bh * SS + f) * 2 + 1];
  }
  __syncthreads();
  for (int s = 1; s <= 11; ++s) {
    const int half = 1 << (s - 1);
    const int m = half << 1;
    const int tshift = 11 - s;
#pragma unroll
    for (int l = 0; l < 4; ++l) {
      int bfly = tid + l * 256;
      int g = bfly >> (s - 1), p = bfly & (half - 1);
      int i0 = g * m + p, i1 = i0 + half;
      int tj = p << tshift;
      float wr_ = twc[tj], wi_ = tws[tj];
      float xr = re[i1], xi = im[i1];
      float tr = wr_ * xr - wi_ * xi;
      float ti = wr_ * xi + wi_ * xr;
      float ur = re[i0], ui = im[i0];
      re[i1] = ur - tr; im[i1] = ui - ti;
      re[i0] = ur + tr; im[i0] = ui + ti;
    }
    __syncthreads();
  }
  unsigned lm = 0u;
#pragma unroll
  for (int l = 0; l < 8; ++l) {
    int i = tid + l * 256;
    float v = re[i] * SCL;
    re[i] = v;
    unsigned u = __float_as_uint(v);
    unsigned k = (u & 0x80000000u) ? ~u : (u | 0x80000000u);
    keys[i] = k;
    lm = max(lm, k);
  }
  atomicMax(&kmax_sh, lm);
  __syncthreads();

  unsigned prefix = 0u;
  int remaining = KTOP;
  for (int p = 3; p >= 0; --p) {
    hist[tid] = 0;
    __syncthreads();
    unsigned mask_hi = (p == 3) ? 0u : (0xFFFFFFFFu << ((p + 1) * 8));
#pragma unroll
    for (int l = 0; l < 8; ++l) {
      unsigned k = keys[tid + l * 256];
      if ((k & mask_hi) == prefix) atomicAdd(&hist[(k >> (p * 8)) & 255], 1);
    }
    __syncthreads();
    scan_sh[tid] = hist[tid];
    __syncthreads();
    for (int off = 1; off < 256; off <<= 1) {
      int add = (tid + off < 256) ? scan_sh[tid + off] : 0;
      __syncthreads();
      scan_sh[tid] += add;
      __syncthreads();
    }
    if (scan_sh[tid] >= remaining && (tid == 255 || scan_sh[tid + 1] < remaining))
      sel_v = tid;
    __syncthreads();
    int v = sel_v;
    int above = (v == 255) ? 0 : scan_sh[v + 1];
    remaining -= above;
    prefix |= ((unsigned)v) << (p * 8);
    __syncthreads();
  }
  const unsigned T = prefix;
  unsigned km = kmax_sh;
  float vmax = __uint_as_float((km & 0x80000000u) ? (km ^ 0x80000000u) : ~km);

#pragma unroll
  for (int l = 0; l < 8; ++l) {
    int i = tid + l * 256;
    unsigned k = keys[i];
    if (k > T) {
      int pos = atomicAdd(&cnt2, 1);
      el_i[pos] = i;
      el_w[pos] = expf(re[i] - vmax);
    } else if (k == T) {
      atomicAdd(&tiecnt, 1);
    }
  }
  __syncthreads();
  int need = KTOP - cnt2;
  if (tiecnt == need) {
#pragma unroll
    for (int l = 0; l < 8; ++l) {
      int i = tid + l * 256;
      if (keys[i] == T) {
        int pos = atomicAdd(&cnt2, 1);
        el_i[pos] = i;
        el_w[pos] = expf(re[i] - vmax);
      }
    }
  } else if (tid == 0) {
    int pos = cnt2;
    for (int i = 0; i < SS && pos < KTOP; ++i)
      if (keys[i] == T) { el_i[pos] = i; el_w[pos] = expf(re[i] - vmax); ++pos; }
  }
  __syncthreads();
  float z = 0.f;
  for (int l = tid; l < KTOP; l += 256) z += el_w[l];
  atomicAdd(&Zsh, z);
  __syncthreads();
  float invZ = 1.0f / Zsh;
  for (int l = tid; l < KTOP; l += 256) {
    sidx[bh * KTOP + l] = el_i[l];
    sw[bh * KTOP + l]   = el_w[l] * invZ;
  }
}

// ---------------- K4: xbar[b,h,:] += sum_slice w * xv[b,idx,:] (split-K) -------
// grid (64 bh, KSL slices). xbar must be zeroed beforehand.
__global__ __launch_bounds__(256) void xbar_k(
    const int* __restrict__ sidx, const float* __restrict__ sw,
    const float* __restrict__ xv, float* __restrict__ xbar)
{
  const int bh = blockIdx.x, b = bh >> 4, sl = blockIdx.y;
  const int r0 = sl * KPS;
  const int r1 = min(KTOP, r0 + KPS);
  __shared__ int il[KPS];
  __shared__ float wl[KPS];
  const int tid = threadIdx.x;
  if (tid < r1 - r0) {
    il[tid] = sidx[bh * KTOP + r0 + tid];
    wl[tid] = sw[bh * KTOP + r0 + tid];
  }
  __syncthreads();
  const float4* xv4 = (const float4*)xv;
  float4 acc = make_float4(0.f, 0.f, 0.f, 0.f);
  for (int r = 0; r < r1 - r0; ++r) {
    float w = wl[r];
    float4 v = xv4[(size_t)(b * SS + il[r]) * 256 + tid];
    acc.x += w * v.x; acc.y += w * v.y; acc.z += w * v.z; acc.w += w * v.w;
  }
  float* dst = xbar + (size_t)bh * 1024 + tid * 4;
  atomicAdd(dst + 0, acc.x); atomicAdd(dst + 1, acc.y);
  atomicAdd(dst + 2, acc.z); atomicAdd(dst + 3, acc.w);
}

// ---------------- K5a: init attended=bv, outrow=bo -----------------------------
__global__ __launch_bounds__(256) void initbias_k(
    const float* __restrict__ bv, const float* __restrict__ bo,
    float* __restrict__ att, float* __restrict__ orow)
{
  int i = blockIdx.x * 256 + threadIdx.x;   // < 8192
  if (i < 4096) att[i] = bv[i & 1023];
  else          orow[i - 4096] = bo[i & 1023];
}

// ---------------- K5: attended[b,j] += sum_i xbar[b,j/64,i]*wv[i,j] ------------
__global__ __launch_bounds__(256) void attend_k(
    const float* __restrict__ xbar, const float* __restrict__ wv,
    float* __restrict__ att)
{
  const int b = blockIdx.y, i0 = blockIdx.x * 64;
  __shared__ float xs[16 * 64];
  const int tid = threadIdx.x;
#pragma unroll
  for (int l = 0; l < 4; ++l) {
    int f = tid + l * 256;
    xs[f] = xbar[(size_t)(b * 16 + (f >> 6)) * 1024 + i0 + (f & 63)];
  }
  __syncthreads();
  const float4* wv4 = (const float4*)wv;
  const int h = tid >> 4;
  float4 acc = make_float4(0.f, 0.f, 0.f, 0.f);
  for (int m = 0; m < 64; ++m) {
    float xvs = xs[h * 64 + m];
    float4 w = wv4[(size_t)(i0 + m) * 256 + tid];
    acc.x += xvs * w.x; acc.y += xvs * w.y; acc.z += xvs * w.z; acc.w += xvs * w.w;
  }
  float* dst = att + (size_t)b * 1024 + tid * 4;
  atomicAdd(dst + 0, acc.x); atomicAdd(dst + 1, acc.y);
  atomicAdd(dst + 2, acc.z); atomicAdd(dst + 3, acc.w);
}

// ---------------- K6: outrow[b,n] += sum_m att[b,m]*wo[m,n] --------------------
__global__ __launch_bounds__(256) void oproj_k(
    const float* __restrict__ att, const float* __restrict__ wo,
    float* __restrict__ orow)
{
  const int b = blockIdx.y, m0 = blockIdx.x * 64;
  __shared__ float as_[64];
  const int tid = threadIdx.x;
  if (tid < 64) as_[tid] = att[(size_t)b * 1024 + m0 + tid];
  __syncthreads();
  const float4* wo4 = (const float4*)wo;
  float4 acc = make_float4(0.f, 0.f, 0.f, 0.f);
  for (int m = 0; m < 64; ++m) {
    float a = as_[m];
    float4 w = wo4[(size_t)(m0 + m) * 256 + tid];
    acc.x += a * w.x; acc.y += a * w.y; acc.z += a * w.z; acc.w += a * w.w;
  }
  float* dst = orow + (size_t)b * 1024 + tid * 4;
  atomicAdd(dst + 0, acc.x); atomicAdd(dst + 1, acc.y);
  atomicAdd(dst + 2, acc.z); atomicAdd(dst + 3, acc.w);
}

// ---------------- K7: broadcast outrow across S --------------------------------
__global__ __launch_bounds__(256) void bcast_k(
    const float* __restrict__ orow, float* __restrict__ out)
{
  int idx = blockIdx.x * 256 + threadIdx.x;           // float4 index
  const float4* o4 = (const float4*)orow;
  ((float4*)out)[idx] = o4[((idx >> 19) << 8) | (idx & 255)];
}

extern "C" void kernel_launch(void* const* d_in, const int* in_sizes, int n_in,
                              void* d_out, int out_size, void* d_ws, size_t ws_size,
                              hipStream_t stream) {
  (void)in_sizes; (void)n_in; (void)out_size; (void)ws_size;
  const float* xq = (const float*)d_in[0];
  const float* xk = (const float*)d_in[1];
  const float* xv = (const float*)d_in[2];
  const float* wq = (const float*)d_in[3];
  const float* bq = (const float*)d_in[4];
  const float* wk = (const float*)d_in[5];
  const float* bk = (const float*)d_in[6];
  const float* wv = (const float*)d_in[7];
  const float* bv = (const float*)d_in[8];
  const float* wo = (const float*)d_in[9];
  const float* bo = (const float*)d_in[10];
  float* out = (float*)d_out;

  // ---- scratch in d_out (32 MB; all dead before bcast_k overwrites it) ----
  char* ob = (char*)d_out;
  float* Qt  = (float*)(ob);                   // 8 MB  [n][t] fp32
  float* Kt  = (float*)(ob + ( 8u << 20));     // 8 MB
  short* Wqt = (short*)(ob + (16u << 20));     // 4 MB
  short* Wkt = (short*)(ob + (20u << 20));     // 4 MB (24..32 MB unused)

  // ---- d_ws: ~2 MB ----
  char* base = (char*)d_ws;
  float* P = (float*)base;                     // B*H*S complex = 1 MB
  size_t off = (size_t)SB * SH * SS * 2 * 4;
  float2* twtab = (float2*)(base + off); off += 1024 * 8;
  int*   sidx = (int*)  (base + off); off += (size_t)SB * SH * KTOP * 4;
  float* sw   = (float*)(base + off); off += (size_t)SB * SH * KTOP * 4;
  float* xbar = (float*)(base + off); off += (size_t)SB * SH * SD * 4;
  float* att  = (float*)(base + off); off += (size_t)SB * SD * 4;
  float* orow = (float*)(base + off);

  twiddle_k<<<dim3(4), 256, 0, stream>>>(twtab);
  splitwt_k<<<dim3(16, 16, 2), 256, 0, stream>>>(wq, wk, Wqt, Wkt);
  hipMemsetAsync(P, 0, (size_t)SB * SH * SS * 2 * sizeof(float), stream);
  hipMemsetAsync(xbar, 0, (size_t)SB * SH * SD * sizeof(float), stream);

  for (int b = 0; b < SB; ++b) {
    proj_k<<<dim3(16, 32, 2), 256, 0, stream>>>(
        xq + (size_t)b * SS * SD, Wqt, bq, Qt,
        xk + (size_t)b * SS * SD, Wkt, bk, Kt);
    fftcorr_k<<<dim3(64, 16), 256, 0, stream>>>(
        Qt, Kt, P + (size_t)b * SH * SS * 2, twtab);
  }
  ifft_topk_k<<<dim3(SB * SH), 256, 0, stream>>>(P, twtab, sidx, sw);
  xbar_k<<<dim3(SB * SH, KSL), 256, 0, stream>>>(sidx, sw, xv, xbar);
  initbias_k<<<dim3(32), 256, 0, stream>>>(bv, bo, att, orow);
  attend_k<<<dim3(16, SB), 256, 0, stream>>>(xbar, wv, att);
  oproj_k<<<dim3(16, SB), 256, 0, stream>>>(att, wo, orow);
  bcast_k<<<dim3(8192), 256, 0, stream>>>(orow, out);
}

// Round 7
// 485.328 us; speedup vs baseline: 1.1409x; 1.1409x over previous
//
#include <hip/hip_runtime.h>
#include <math.h>

#define SB 4
#define SS 2048
#define SD 1024
#define SH 16
#define KTOP 409   // max(2048//5, 1)
#define KSL 8      // xbar split-K slices
#define KPS 52     // ceil(KTOP/KSL)

typedef float f32x4  __attribute__((ext_vector_type(4)));
typedef short bf16x8 __attribute__((ext_vector_type(8)));
typedef short s16x4  __attribute__((ext_vector_type(4)));

__device__ __forceinline__ short f2bf(float x) {
  unsigned u = __float_as_uint(x);
  u += 0x7fff + ((u >> 16) & 1);           // RNE
  return (short)(u >> 16);
}
__device__ __forceinline__ float bf2f(short s) {
  return __uint_as_float(((unsigned)(unsigned short)s) << 16);
}

// padded LDS index: one extra float2 every 32 elements (breaks pow2-stride conflicts)
#define FPAD(i) ((i) + ((i) >> 5))
#define ZLEN 2112   // FPAD(2047)+1 = 2110, rounded up

// ---- shared 2048-pt FFT core: radix-2 stage + 5 fused radix-4 DIT stages ------
// Input: z[FPAD(i)] holds bit-reversed(11)-loaded samples. tw[j]=exp(-2pi i j/2048).
// SIGN=+1 forward, -1 inverse (twiddles conjugated + W4 conjugated). Natural-order out.
template<int SIGN>
__device__ __forceinline__ void fft2048_lds(float2* z, const float2* tw, int tid) {
  // stage 1: radix-2, no twiddle
#pragma unroll
  for (int l = 0; l < 4; ++l) {
    int bf = tid + l * 256;                 // 0..1023
    int i0 = FPAD(2 * bf), i1 = FPAD(2 * bf + 1);
    float2 a = z[i0], b = z[i1];
    z[i0] = make_float2(a.x + b.x, a.y + b.y);
    z[i1] = make_float2(a.x - b.x, a.y - b.y);
  }
  __syncthreads();
  // fused radix-4 stages: q = 2,8,32,128,512 (sub-DFT size), M=4q, s = 512/q
#pragma unroll
  for (int lq = 1; lq <= 9; lq += 2) {
    const int q = 1 << lq;
#pragma unroll
    for (int l = 0; l < 2; ++l) {
      int bf = tid + l * 256;               // 0..511
      int p = bf & (q - 1);
      int base = ((bf >> lq) << (lq + 2)) + p;
      int e1 = p << (9 - lq);               // p * 512/q  (< 512)
      int e2 = e1 << 1;                     // < 1024
      int e3 = e1 * 3;                      // < 1536, wrap at 1024 (tw[j+1024] = -tw[j])
      float2 w1 = tw[e1];
      float2 w2 = tw[e2];
      float s3 = 1.f; int e3w = e3;
      if (e3 >= 1024) { e3w = e3 - 1024; s3 = -1.f; }
      float2 w3 = tw[e3w]; w3.x *= s3; w3.y *= s3;
      // sub-blocks within [base, base+4q) hold j = 0,2,1,3 (bit-reversed pair order)
      float2 t0 = z[FPAD(base)];
      float2 vb = z[FPAD(base + 2 * q)];    // j=1
      float2 vc = z[FPAD(base + q)];        // j=2
      float2 vd = z[FPAD(base + 3 * q)];    // j=3
      float w1i = SIGN * w1.y, w2i = SIGN * w2.y, w3i = SIGN * w3.y;
      float2 t1 = make_float2(vb.x * w1.x - vb.y * w1i, vb.x * w1i + vb.y * w1.x);
      float2 t2 = make_float2(vc.x * w2.x - vc.y * w2i, vc.x * w2i + vc.y * w2.x);
      float2 t3 = make_float2(vd.x * w3.x - vd.y * w3i, vd.x * w3i + vd.y * w3.x);
      float2 s02 = make_float2(t0.x + t2.x, t0.y + t2.y);
      float2 d02 = make_float2(t0.x - t2.x, t0.y - t2.y);
      float2 s13 = make_float2(t1.x + t3.x, t1.y + t3.y);
      float2 d13 = make_float2(t1.x - t3.x, t1.y - t3.y);
      float2 r13 = make_float2(SIGN * d13.y, -SIGN * d13.x);   // (-i*SIGN)*d13
      z[FPAD(base)]         = make_float2(s02.x + s13.x, s02.y + s13.y);
      z[FPAD(base + q)]     = make_float2(d02.x + r13.x, d02.y + r13.y);
      z[FPAD(base + 2 * q)] = make_float2(s02.x - s13.x, s02.y - s13.y);
      z[FPAD(base + 3 * q)] = make_float2(d02.x - r13.x, d02.y - r13.y);
    }
    __syncthreads();
  }
}

// ---------------- P-1: forward twiddle table w_j = exp(-2pi i j/2048) ----------
__global__ __launch_bounds__(256) void twiddle_k(float2* __restrict__ twtab) {
  int j = blockIdx.x * 256 + threadIdx.x;   // < 1024
  float a = 6.2831853071795864769f * (float)j / 2048.0f;
  twtab[j] = make_float2(cosf(a), -sinf(a));
}

// ---------------- P0: transpose + split W[k][n] -> Wt[n][{hi:0..1023|lo:1024..2047}]
__global__ __launch_bounds__(256) void splitwt_k(
    const float* __restrict__ wq, const float* __restrict__ wk,
    short* __restrict__ wqt, short* __restrict__ wkt)
{
  const float* W = blockIdx.z ? wk : wq;
  short* Wt = blockIdx.z ? wkt : wqt;
  const int n0 = blockIdx.x * 64, k0 = blockIdx.y * 64;
  __shared__ float T[64][65];
  const int tid = threadIdx.x;
#pragma unroll
  for (int l = 0; l < 4; ++l) {
    int idx = tid + l * 256;
    int r = idx >> 4, c4 = (idx & 15) << 2;
    float4 v = *(const float4*)&W[(size_t)(k0 + r) * SD + n0 + c4];
    T[r][c4 + 0] = v.x; T[r][c4 + 1] = v.y; T[r][c4 + 2] = v.z; T[r][c4 + 3] = v.w;
  }
  __syncthreads();
#pragma unroll
  for (int l = 0; l < 4; ++l) {
    int idx = tid + l * 256;
    int nr = idx >> 4, k4 = (idx & 15) << 2;
    s16x4 hi, lo;
#pragma unroll
    for (int j = 0; j < 4; ++j) {
      float x = T[k4 + j][nr];
      short hb = f2bf(x);
      hi[j] = hb; lo[j] = f2bf(x - bf2f(hb));
    }
    *(s16x4*)&Wt[(size_t)(n0 + nr) * 2048 + k0 + k4] = hi;
    *(s16x4*)&Wt[(size_t)(n0 + nr) * 2048 + 1024 + k0 + k4] = lo;
  }
}

// ---------------- K1: split-bf16 MFMA projection (16x16x32), 64x64 tile --------
// grid (16 n, 32 m, 2 {q,k}), block 256 = 4 waves in 2x2, 32x32 per wave.
__global__ __launch_bounds__(256) void proj_k(
    const float* __restrict__ xq, const short* __restrict__ Wq,
    const float* __restrict__ bq, float* __restrict__ Qt,
    const float* __restrict__ xk, const short* __restrict__ Wk,
    const float* __restrict__ bk, float* __restrict__ Kt)
{
  const float* X; const short* Wt; const float* bias; float* Out;
  if (blockIdx.z == 0) { X = xq; Wt = Wq; bias = bq; Out = Qt; }
  else                 { X = xk; Wt = Wk; bias = bk; Out = Kt; }
  const int n0 = blockIdx.x * 64, m0 = blockIdx.y * 64;
  __shared__ __align__(16) short Ah[64 * 64];
  __shared__ __align__(16) short Al[64 * 64];
  __shared__ __align__(16) short Bh[64 * 64];
  __shared__ __align__(16) short Bl[64 * 64];
  const int tid = threadIdx.x;
  const int wave = tid >> 6, lane = tid & 63, l15 = lane & 15, kq = lane >> 4;
  const int wr = wave >> 1, wc = wave & 1;
  f32x4 acc[2][2];
#pragma unroll
  for (int i = 0; i < 2; ++i)
#pragma unroll
    for (int j = 0; j < 2; ++j)
#pragma unroll
      for (int r = 0; r < 4; ++r) acc[i][j][r] = 0.f;
  float bval[2];
#pragma unroll
  for (int j = 0; j < 2; ++j) bval[j] = bias[n0 + wc * 32 + j * 16 + l15];

  for (int s = 0; s < 16; ++s) {
    __syncthreads();
#pragma unroll
    for (int l = 0; l < 2; ++l) {
      int idx = tid + l * 256;
      int row = idx >> 3, seg = idx & 7;
      const float* src = &X[(size_t)(m0 + row) * SD + s * 64 + seg * 8];
      float4 va = *(const float4*)src;
      float4 vb = *(const float4*)(src + 4);
      float xs[8] = {va.x, va.y, va.z, va.w, vb.x, vb.y, vb.z, vb.w};
      bf16x8 hi, lo;
#pragma unroll
      for (int j = 0; j < 8; ++j) {
        short hb = f2bf(xs[j]);
        hi[j] = hb; lo[j] = f2bf(xs[j] - bf2f(hb));
      }
      int dst = row * 64 + ((seg ^ (row & 7)) << 3);
      *(bf16x8*)&Ah[dst] = hi;
      *(bf16x8*)&Al[dst] = lo;
    }
#pragma unroll
    for (int l = 0; l < 2; ++l) {
      int idx = tid + l * 256;
      int row = idx >> 3, seg = idx & 7;
      int d = row * 64 + ((seg ^ (row & 7)) << 3);
      *(bf16x8*)&Bh[d] = *(const bf16x8*)&Wt[(size_t)(n0 + row) * 2048 + s * 64 + seg * 8];
      *(bf16x8*)&Bl[d] = *(const bf16x8*)&Wt[(size_t)(n0 + row) * 2048 + 1024 + s * 64 + seg * 8];
    }
    __syncthreads();
#pragma unroll
    for (int ks = 0; ks < 2; ++ks) {
      int seg = ks * 4 + kq;
      bf16x8 ah[2], al[2], bh[2], bl[2];
#pragma unroll
      for (int i = 0; i < 2; ++i) {
        int ar = wr * 32 + i * 16 + l15;
        int addr = ar * 64 + ((seg ^ (ar & 7)) << 3);
        ah[i] = *(const bf16x8*)&Ah[addr];
        al[i] = *(const bf16x8*)&Al[addr];
      }
#pragma unroll
      for (int j = 0; j < 2; ++j) {
        int br = wc * 32 + j * 16 + l15;
        int addr = br * 64 + ((seg ^ (br & 7)) << 3);
        bh[j] = *(const bf16x8*)&Bh[addr];
        bl[j] = *(const bf16x8*)&Bl[addr];
      }
#pragma unroll
      for (int i = 0; i < 2; ++i)
#pragma unroll
        for (int j = 0; j < 2; ++j) {
          acc[i][j] = __builtin_amdgcn_mfma_f32_16x16x32_bf16(ah[i], bh[j], acc[i][j], 0, 0, 0);
          acc[i][j] = __builtin_amdgcn_mfma_f32_16x16x32_bf16(al[i], bh[j], acc[i][j], 0, 0, 0);
          acc[i][j] = __builtin_amdgcn_mfma_f32_16x16x32_bf16(ah[i], bl[j], acc[i][j], 0, 0, 0);
        }
    }
  }
#pragma unroll
  for (int i = 0; i < 2; ++i)
#pragma unroll
    for (int j = 0; j < 2; ++j) {
      int n = n0 + wc * 32 + j * 16 + l15;
      int tb = m0 + wr * 32 + i * 16 + kq * 4;
      float4 v = make_float4(acc[i][j][0] + bval[j], acc[i][j][1] + bval[j],
                             acc[i][j][2] + bval[j], acc[i][j][3] + bval[j]);
      *(float4*)&Out[(size_t)n * SS + tb] = v;
    }
}

// ---------------- K2: packed FFT (re=q, im=k) + cross-spectrum accumulate ------
// grid (32 dgroups, 16 heads) per batch; 2 columns per block, register accum.
__global__ __launch_bounds__(256) void fftcorr_k(
    const float* __restrict__ Qt, const float* __restrict__ Kt,
    float* __restrict__ Pb, const float2* __restrict__ twtab)
{
  const int dg = blockIdx.x, h = blockIdx.y;
  __shared__ float2 z[ZLEN];
  __shared__ float2 tw[1024];
  const int tid = threadIdx.x;
  for (int j = tid; j < 1024; j += 256) tw[j] = twtab[j];
  float prr[8], pii[8];
#pragma unroll
  for (int l = 0; l < 8; ++l) { prr[l] = 0.f; pii[l] = 0.f; }

  for (int dd = 0; dd < 2; ++dd) {
    const int n = h * 64 + dg * 2 + dd;
    __syncthreads();
#pragma unroll
    for (int l = 0; l < 8; ++l) {
      int t = tid + l * 256;
      int rv = __brev((unsigned)t) >> 21;
      z[FPAD(rv)] = make_float2(Qt[(size_t)n * SS + t], Kt[(size_t)n * SS + t]);
    }
    __syncthreads();
    fft2048_lds<1>(z, tw, tid);
    // unpack two real spectra; P += Qf * conj(Kf)
#pragma unroll
    for (int l = 0; l < 8; ++l) {
      int f = tid + l * 256;
      int fc = (2048 - f) & 2047;
      float2 Z = z[FPAD(f)];
      float2 Zc = z[FPAD(fc)];
      float Zcr = Zc.x, Zci = -Zc.y;
      float Qr = 0.5f * (Z.x + Zcr), Qi = 0.5f * (Z.y + Zci);
      float Kr = 0.5f * (Z.y - Zci), Ki = -0.5f * (Z.x - Zcr);
      prr[l] += Qr * Kr + Qi * Ki;
      pii[l] += Qi * Kr - Qr * Ki;
    }
  }
#pragma unroll
  for (int l = 0; l < 8; ++l) {
    int f = tid + l * 256;
    atomicAdd(&Pb[((size_t)h * SS + f) * 2 + 0], prr[l]);
    atomicAdd(&Pb[((size_t)h * SS + f) * 2 + 1], pii[l]);
  }
}

// ---------------- K3: inverse FFT + byte-radix top-409 + softmax, per (b,h) ----
__global__ __launch_bounds__(256) void ifft_topk_k(
    const float* __restrict__ P, const float2* __restrict__ twtab,
    int* __restrict__ sidx, float* __restrict__ sw)
{
  const int bh = blockIdx.x;
  __shared__ float2 z[ZLEN];
  __shared__ float2 tw[1024];
  __shared__ unsigned keys[2048];
  __shared__ int el_i[KTOP];
  __shared__ float el_w[KTOP];
  __shared__ int hist[256];
  __shared__ int scan_sh[256];
  __shared__ int cnt2, tiecnt, sel_v;
  __shared__ unsigned kmax_sh;
  __shared__ float Zsh;
  const int tid = threadIdx.x;
  const float SCL = 1.0f / (2048.0f * 512.0f);   // 1/N * 1/(dh*sqrt(dh))

  for (int j = tid; j < 1024; j += 256) tw[j] = twtab[j];
  if (tid == 0) { cnt2 = 0; tiecnt = 0; kmax_sh = 0u; Zsh = 0.f; }
#pragma unroll
  for (int l = 0; l < 8; ++l) {
    int f = tid + l * 256;
    int rv = __brev((unsigned)f) >> 21;
    z[FPAD(rv)] = make_float2(P[((size_t)bh * SS + f) * 2 + 0],
                              P[((size_t)bh * SS + f) * 2 + 1]);
  }
  __syncthreads();
  fft2048_lds<-1>(z, tw, tid);

  unsigned lm = 0u;
#pragma unroll
  for (int l = 0; l < 8; ++l) {
    int i = tid + l * 256;
    float v = z[FPAD(i)].x * SCL;
    z[FPAD(i)].x = v;
    unsigned u = __float_as_uint(v);
    unsigned k = (u & 0x80000000u) ? ~u : (u | 0x80000000u);
    keys[i] = k;
    lm = max(lm, k);
  }
  atomicMax(&kmax_sh, lm);
  __syncthreads();

  unsigned prefix = 0u;
  int remaining = KTOP;
  for (int p = 3; p >= 0; --p) {
    hist[tid] = 0;
    __syncthreads();
    unsigned mask_hi = (p == 3) ? 0u : (0xFFFFFFFFu << ((p + 1) * 8));
#pragma unroll
    for (int l = 0; l < 8; ++l) {
      unsigned k = keys[tid + l * 256];
      if ((k & mask_hi) == prefix) atomicAdd(&hist[(k >> (p * 8)) & 255], 1);
    }
    __syncthreads();
    scan_sh[tid] = hist[tid];
    __syncthreads();
    for (int off = 1; off < 256; off <<= 1) {
      int add = (tid + off < 256) ? scan_sh[tid + off] : 0;
      __syncthreads();
      scan_sh[tid] += add;
      __syncthreads();
    }
    if (scan_sh[tid] >= remaining && (tid == 255 || scan_sh[tid + 1] < remaining))
      sel_v = tid;
    __syncthreads();
    int v = sel_v;
    int above = (v == 255) ? 0 : scan_sh[v + 1];
    remaining -= above;
    prefix |= ((unsigned)v) << (p * 8);
    __syncthreads();
  }
  const unsigned T = prefix;
  unsigned km = kmax_sh;
  float vmax = __uint_as_float((km & 0x80000000u) ? (km ^ 0x80000000u) : ~km);

#pragma unroll
  for (int l = 0; l < 8; ++l) {
    int i = tid + l * 256;
    unsigned k = keys[i];
    if (k > T) {
      int pos = atomicAdd(&cnt2, 1);
      el_i[pos] = i;
      el_w[pos] = expf(z[FPAD(i)].x - vmax);
    } else if (k == T) {
      atomicAdd(&tiecnt, 1);
    }
  }
  __syncthreads();
  int need = KTOP - cnt2;
  if (tiecnt == need) {
#pragma unroll
    for (int l = 0; l < 8; ++l) {
      int i = tid + l * 256;
      if (keys[i] == T) {
        int pos = atomicAdd(&cnt2, 1);
        el_i[pos] = i;
        el_w[pos] = expf(z[FPAD(i)].x - vmax);
      }
    }
  } else if (tid == 0) {
    int pos = cnt2;
    for (int i = 0; i < SS && pos < KTOP; ++i)
      if (keys[i] == T) { el_i[pos] = i; el_w[pos] = expf(z[FPAD(i)].x - vmax); ++pos; }
  }
  __syncthreads();
  float zs = 0.f;
  for (int l = tid; l < KTOP; l += 256) zs += el_w[l];
  atomicAdd(&Zsh, zs);
  __syncthreads();
  float invZ = 1.0f / Zsh;
  for (int l = tid; l < KTOP; l += 256) {
    sidx[bh * KTOP + l] = el_i[l];
    sw[bh * KTOP + l]   = el_w[l] * invZ;
  }
}

// ---------------- K4: xbar[b,h,:] += sum_slice w * xv[b,idx,:] (split-K) -------
__global__ __launch_bounds__(256) void xbar_k(
    const int* __restrict__ sidx, const float* __restrict__ sw,
    const float* __restrict__ xv, float* __restrict__ xbar)
{
  const int bh = blockIdx.x, b = bh >> 4, sl = blockIdx.y;
  const int r0 = sl * KPS;
  const int r1 = min(KTOP, r0 + KPS);
  __shared__ int il[KPS];
  __shared__ float wl[KPS];
  const int tid = threadIdx.x;
  if (tid < r1 - r0) {
    il[tid] = sidx[bh * KTOP + r0 + tid];
    wl[tid] = sw[bh * KTOP + r0 + tid];
  }
  __syncthreads();
  const float4* xv4 = (const float4*)xv;
  float4 acc = make_float4(0.f, 0.f, 0.f, 0.f);
  for (int r = 0; r < r1 - r0; ++r) {
    float w = wl[r];
    float4 v = xv4[(size_t)(b * SS + il[r]) * 256 + tid];
    acc.x += w * v.x; acc.y += w * v.y; acc.z += w * v.z; acc.w += w * v.w;
  }
  float* dst = xbar + (size_t)bh * 1024 + tid * 4;
  atomicAdd(dst + 0, acc.x); atomicAdd(dst + 1, acc.y);
  atomicAdd(dst + 2, acc.z); atomicAdd(dst + 3, acc.w);
}

// ---------------- K5a: init attended=bv, outrow=bo -----------------------------
__global__ __launch_bounds__(256) void initbias_k(
    const float* __restrict__ bv, const float* __restrict__ bo,
    float* __restrict__ att, float* __restrict__ orow)
{
  int i = blockIdx.x * 256 + threadIdx.x;   // < 8192
  if (i < 4096) att[i] = bv[i & 1023];
  else          orow[i - 4096] = bo[i & 1023];
}

// ---------------- K5: attended[b,j] += sum_i xbar[b,j/64,i]*wv[i,j] ------------
__global__ __launch_bounds__(256) void attend_k(
    const float* __restrict__ xbar, const float* __restrict__ wv,
    float* __restrict__ att)
{
  const int b = blockIdx.y, i0 = blockIdx.x * 64;
  __shared__ float xs[16 * 64];
  const int tid = threadIdx.x;
#pragma unroll
  for (int l = 0; l < 4; ++l) {
    int f = tid + l * 256;
    xs[f] = xbar[(size_t)(b * 16 + (f >> 6)) * 1024 + i0 + (f & 63)];
  }
  __syncthreads();
  const float4* wv4 = (const float4*)wv;
  const int h = tid >> 4;
  float4 acc = make_float4(0.f, 0.f, 0.f, 0.f);
  for (int m = 0; m < 64; ++m) {
    float xvs = xs[h * 64 + m];
    float4 w = wv4[(size_t)(i0 + m) * 256 + tid];
    acc.x += xvs * w.x; acc.y += xvs * w.y; acc.z += xvs * w.z; acc.w += xvs * w.w;
  }
  float* dst = att + (size_t)b * 1024 + tid * 4;
  atomicAdd(dst + 0, acc.x); atomicAdd(dst + 1, acc.y);
  atomicAdd(dst + 2, acc.z); atomicAdd(dst + 3, acc.w);
}

// ---------------- K6: outrow[b,n] += sum_m att[b,m]*wo[m,n] --------------------
__global__ __launch_bounds__(256) void oproj_k(
    const float* __restrict__ att, const float* __restrict__ wo,
    float* __restrict__ orow)
{
  const int b = blockIdx.y, m0 = blockIdx.x * 64;
  __shared__ float as_[64];
  const int tid = threadIdx.x;
  if (tid < 64) as_[tid] = att[(size_t)b * 1024 + m0 + tid];
  __syncthreads();
  const float4* wo4 = (const float4*)wo;
  float4 acc = make_float4(0.f, 0.f, 0.f, 0.f);
  for (int m = 0; m < 64; ++m) {
    float a = as_[m];
    float4 w = wo4[(size_t)(m0 + m) * 256 + tid];
    acc.x += a * w.x; acc.y += a * w.y; acc.z += a * w.z; acc.w += a * w.w;
  }
  float* dst = orow + (size_t)b * 1024 + tid * 4;
  atomicAdd(dst + 0, acc.x); atomicAdd(dst + 1, acc.y);
  atomicAdd(dst + 2, acc.z); atomicAdd(dst + 3, acc.w);
}

// ---------------- K7: broadcast outrow across S --------------------------------
__global__ __launch_bounds__(256) void bcast_k(
    const float* __restrict__ orow, float* __restrict__ out)
{
  int idx = blockIdx.x * 256 + threadIdx.x;           // float4 index
  const float4* o4 = (const float4*)orow;
  ((float4*)out)[idx] = o4[((idx >> 19) << 8) | (idx & 255)];
}

extern "C" void kernel_launch(void* const* d_in, const int* in_sizes, int n_in,
                              void* d_out, int out_size, void* d_ws, size_t ws_size,
                              hipStream_t stream) {
  (void)in_sizes; (void)n_in; (void)out_size; (void)ws_size;
  const float* xq = (const float*)d_in[0];
  const float* xk = (const float*)d_in[1];
  const float* xv = (const float*)d_in[2];
  const float* wq = (const float*)d_in[3];
  const float* bq = (const float*)d_in[4];
  const float* wk = (const float*)d_in[5];
  const float* bk = (const float*)d_in[6];
  const float* wv = (const float*)d_in[7];
  const float* bv = (const float*)d_in[8];
  const float* wo = (const float*)d_in[9];
  const float* bo = (const float*)d_in[10];
  float* out = (float*)d_out;

  // ---- scratch in d_out (32 MB; all dead before bcast_k overwrites it) ----
  char* ob = (char*)d_out;
  float* Qt  = (float*)(ob);                   // 8 MB  [n][t] fp32
  float* Kt  = (float*)(ob + ( 8u << 20));     // 8 MB
  short* Wqt = (short*)(ob + (16u << 20));     // 4 MB
  short* Wkt = (short*)(ob + (20u << 20));     // 4 MB (24..32 MB unused)

  // ---- d_ws: ~2 MB ----
  char* base = (char*)d_ws;
  float* P = (float*)base;                     // B*H*S complex = 1 MB
  size_t off = (size_t)SB * SH * SS * 2 * 4;
  float2* twtab = (float2*)(base + off); off += 1024 * 8;
  int*   sidx = (int*)  (base + off); off += (size_t)SB * SH * KTOP * 4;
  float* sw   = (float*)(base + off); off += (size_t)SB * SH * KTOP * 4;
  float* xbar = (float*)(base + off); off += (size_t)SB * SH * SD * 4;
  float* att  = (float*)(base + off); off += (size_t)SB * SD * 4;
  float* orow = (float*)(base + off);

  twiddle_k<<<dim3(4), 256, 0, stream>>>(twtab);
  splitwt_k<<<dim3(16, 16, 2), 256, 0, stream>>>(wq, wk, Wqt, Wkt);
  hipMemsetAsync(P, 0, (size_t)SB * SH * SS * 2 * sizeof(float), stream);
  hipMemsetAsync(xbar, 0, (size_t)SB * SH * SD * sizeof(float), stream);

  for (int b = 0; b < SB; ++b) {
    proj_k<<<dim3(16, 32, 2), 256, 0, stream>>>(
        xq + (size_t)b * SS * SD, Wqt, bq, Qt,
        xk + (size_t)b * SS * SD, Wkt, bk, Kt);
    fftcorr_k<<<dim3(32, 16), 256, 0, stream>>>(
        Qt, Kt, P + (size_t)b * SH * SS * 2, twtab);
  }
  ifft_topk_k<<<dim3(SB * SH), 256, 0, stream>>>(P, twtab, sidx, sw);
  xbar_k<<<dim3(SB * SH, KSL), 256, 0, stream>>>(sidx, sw, xv, xbar);
  initbias_k<<<dim3(32), 256, 0, stream>>>(bv, bo, att, orow);
  attend_k<<<dim3(16, SB), 256, 0, stream>>>(xbar, wv, att);
  oproj_k<<<dim3(16, SB), 256, 0, stream>>>(att, wo, orow);
  bcast_k<<<dim3(8192), 256, 0, stream>>>(orow, out);
}